// Round 14
// baseline (115.718 us; speedup 1.0000x reference)
//
#include <hip/hip_runtime.h>

// ConvQuadInterp3d: 3x3x3 replicate-padded stencil, quadratic peak refinement.
// Input  x: FP32, (2,1,10,512,512)
// Output: FP32, coords_max (2,1,3,10,512,512) ++ y_max (2,1,10,512,512)
// Coords channel order: jax source order ch0=d+dx2, ch1=h+dx1, ch2=w+dx0.
//
// R13 post-mortem: kernel ~35us vs ~17us traffic floor; R9-vs-R13 comparison
// shows VMEM issue count is NOT the limiter (latency/L1-service is). R13's 27
// unaligned loads/wave occupy L1 ~135 cyc/wave. R14: lane loads only its own
// w (9 coalesced loads); w+-1 comes from __shfl_up/down on the LDS pipe
// (overlaps L1/VALU); wave-edge lanes patch via 2-lane-masked loads (9 instrs,
// ~2 lines each). L1 service ~63 cyc/wave, TLP unchanged (320 waves/CU).
//
// NaN discipline: fast-math-safe by construction — keep = |num| <= 0.7*|det|
// evaluated WITHOUT dividing; 1/det only taken when keep (=> det != 0).

constexpr int Dd = 10, Hh = 512, Ww = 512;
constexpr int HW  = Hh * Ww;        // 262144
constexpr int DHW = Dd * HW;        // 2621440
constexpr float BONUS_F = 10.0f;

__global__ __launch_bounds__(256) void quad_kernel(
        const float* __restrict__ x, float* __restrict__ out) {
    const int tx = threadIdx.x;                       // lane 0..63 (wave = one h-row)
    const int w  = (blockIdx.x << 6) + tx;            // 0..511
    const int h  = (blockIdx.y << 2) + threadIdx.y;
    const int bd = blockIdx.z;                        // 0..19: b*Dd + d
    const int d  = bd % Dd;
    const int b  = bd / Dd;

    // replicate-clamped neighbor indices
    const int wm = (w == 0) ? 0 : w - 1,      wp = (w == Ww - 1) ? w : w + 1;
    const int hm = (h == 0) ? h : h - 1,      hp = (h == Hh - 1) ? h : h + 1;
    const int zm = (d == 0) ? bd : bd - 1,    zp = (d == Dd - 1) ? bd : bd + 1;

    const float* r0 = x + (size_t)zm * HW + (size_t)hm * Ww;  // z-1, y-1
    const float* r1 = x + (size_t)zm * HW + (size_t)h  * Ww;  // z-1, y
    const float* r2 = x + (size_t)zm * HW + (size_t)hp * Ww;  // z-1, y+1
    const float* r3 = x + (size_t)bd * HW + (size_t)hm * Ww;  // z  , y-1
    const float* r4 = x + (size_t)bd * HW + (size_t)h  * Ww;  // z  , y
    const float* r5 = x + (size_t)bd * HW + (size_t)hp * Ww;  // z  , y+1
    const float* r6 = x + (size_t)zp * HW + (size_t)hm * Ww;  // z+1, y-1
    const float* r7 = x + (size_t)zp * HW + (size_t)h  * Ww;  // z+1, y
    const float* r8 = x + (size_t)zp * HW + (size_t)hp * Ww;  // z+1, y+1

    // Own-w values: 9 fully-coalesced scalar loads.
    float vc[9];
    vc[0] = r0[w]; vc[1] = r1[w]; vc[2] = r2[w];
    vc[3] = r3[w]; vc[4] = r4[w]; vc[5] = r5[w];
    vc[6] = r6[w]; vc[7] = r7[w]; vc[8] = r8[w];

    // w-1 / w+1 via cross-lane shuffle (LDS pipe); wave-edge lanes patch with
    // a 2-active-lane masked load per row (touches <=2 cache lines).
    const bool lane0 = (tx == 0), lane63 = (tx == 63);
    const int  we = lane0 ? wm : wp;                  // edge address per lane
    float vl[9], vr[9];
#pragma unroll
    for (int r = 0; r < 9; ++r) {
        const float* rp = (r == 0) ? r0 : (r == 1) ? r1 : (r == 2) ? r2 :
                          (r == 3) ? r3 : (r == 4) ? r4 : (r == 5) ? r5 :
                          (r == 6) ? r6 : (r == 7) ? r7 : r8;
        float e = 0.0f;
        if (lane0 || lane63) e = rp[we];              // exec-masked load
        const float up = __shfl_up(vc[r], 1, 64);     // lane i <- lane i-1
        const float dn = __shfl_down(vc[r], 1, 64);   // lane i <- lane i+1
        vl[r] = lane0  ? e : up;
        vr[r] = lane63 ? e : dn;
    }

    // nmax = max(26 neighbors, 0); replicate padding at faces puts the center
    // into the neighbor set -> m false there (matches ref).
    const float xc = vc[4];
    float nm = 0.0f;
#pragma unroll
    for (int r = 0; r < 9; ++r) {
        nm = fmaxf(nm, vl[r]);
        nm = fmaxf(nm, vr[r]);
        if (r != 4) nm = fmaxf(nm, vc[r]);
    }
    const bool m = xc > nm;

    const float gx  = 0.5f * (vr[4] - vl[4]);
    const float gy  = 0.5f * (vc[5] - vc[3]);
    const float gs  = 0.5f * (vc[7] - vc[1]);
    const float dxx = vl[4] + vr[4] - 2.0f * xc;
    const float dyy = vc[3] + vc[5] - 2.0f * xc;
    const float dss = vc[1] + vc[7] - 2.0f * xc;
    const float dxy = 0.25f * (vl[3] + vr[5] - vl[5] - vr[3]);
    const float dys = 0.25f * (vc[0] + vc[8] - vc[2] - vc[6]);
    const float dxs = 0.25f * (vl[1] + vr[7] - vl[7] - vr[1]);

    // Cramer numerators of H*s = g. Rm eps (<=1e-7) dropped: near-singular
    // dets rejected by keep, like ref's far>0.7 clamp of eps-regularized dx.
    const float c00 = dyy * dss - dys * dys;
    const float c01 = dxy * dss - dys * dxs;
    const float c02 = dxy * dys - dyy * dxs;
    const float det = dxx * c00 - dxy * c01 + dxs * c02;
    const float t1  = gy * dss - dys * gs;
    const float t2  = gy * dys - dyy * gs;
    const float t3  = dxy * gs - gy * dxs;
    const float nx  = gx * c00 - dxy * t1 + dxs * t2;    // sx * det
    const float ny  = dxx * t1 - gx * c01 + dxs * t3;    // sy * det
    const float ns  = dxx * (-t2) - dxy * t3 + gx * c02; // ss * det

    // keep <=> m && det!=0 && all |num/det| <= 0.7, WITHOUT dividing.
    const float lim = 0.7f * fabsf(det);
    const bool keep = m && (fabsf(det) > 0.0f) &&
                      (fabsf(nx) <= lim) && (fabsf(ny) <= lim) && (fabsf(ns) <= lim);
    const float rdet = keep ? (1.0f / det) : 0.0f;
    const float dx0 = -nx * rdet;                   // keep ? -nx/det : 0  (finite)
    const float dx1 = -ny * rdet;
    const float dx2 = -ns * rdet;

    const float dy_ = 0.5f * (gx * dx0 + gy * dx1 + gs * dx2);
    const float y   = xc + dy_ + (m ? BONUS_F : 0.0f);

    const size_t idx = (size_t)d * HW + (size_t)h * Ww + w;
    out[((size_t)(b * 3 + 0)) * DHW + idx] = (float)d + dx2;
    out[((size_t)(b * 3 + 1)) * DHW + idx] = (float)h + dx1;
    out[((size_t)(b * 3 + 2)) * DHW + idx] = (float)w + dx0;
    out[(size_t)6 * DHW + (size_t)b * DHW + idx] = y;
}

extern "C" void kernel_launch(void* const* d_in, const int* in_sizes, int n_in,
                              void* d_out, int out_size, void* d_ws, size_t ws_size,
                              hipStream_t stream) {
    (void)in_sizes; (void)n_in; (void)out_size; (void)d_ws; (void)ws_size;
    const float* x = (const float*)d_in[0];
    float* out = (float*)d_out;
    dim3 block(64, 4, 1);
    dim3 grid(Ww / 64, Hh / 4, 2 * Dd);   // (8, 128, 20) = 20480 blocks
    quad_kernel<<<grid, block, 0, stream>>>(x, out);
}

// Round 15
// 108.046 us; speedup vs baseline: 1.0710x; 1.0710x over previous
//
#include <hip/hip_runtime.h>

// ConvQuadInterp3d: 3x3x3 replicate-padded stencil, quadratic peak refinement.
// Input  x: FP32, (2,1,10,512,512)
// Output: FP32, coords_max (2,1,3,10,512,512) ++ y_max (2,1,10,512,512)
// Coords channel order: jax source order ch0=d+dx2, ch1=h+dx1, ch2=w+dx0.
//
// R14 post-mortem: shuffle variant regressed (41us vs R13's 35us) -> L1
// service is NOT binding; instruction issue is. R15: h-PAIRED outputs —
// one thread does (h0,w) and (h0+1,w). The pair's neighborhoods share
// 18 of 54 loads (36 loads / 2 outputs = 18/output vs R13's 27) and a
// 16-value sub-max of the 26-neighbor max (35 fmax vs 52). Coalescing
// structure of R13 preserved (scalar coalesced loads/stores, lane = w).
//
// NaN discipline: fast-math-safe by construction — keep = |num| <= 0.7*|det|
// evaluated WITHOUT dividing; 1/det only taken when keep (=> det != 0).

constexpr int Dd = 10, Hh = 512, Ww = 512;
constexpr int HW  = Hh * Ww;        // 262144
constexpr int DHW = Dd * HW;        // 2621440
constexpr float BONUS_F = 10.0f;

__global__ __launch_bounds__(256) void quad_kernel(
        const float* __restrict__ x, float* __restrict__ out) {
    const int tx = threadIdx.x;                       // lane 0..63 (lane = w)
    const int w  = (blockIdx.x << 6) + tx;            // 0..511
    const int h0 = (blockIdx.y << 3) + (threadIdx.y << 1);  // even row of the pair
    const int bd = blockIdx.z;                        // 0..19: b*Dd + d
    const int d  = bd % Dd;
    const int b  = bd / Dd;

    // replicate-clamped indices
    const int wm = (w == 0) ? 0 : w - 1,      wp = (w == Ww - 1) ? w : w + 1;
    const int zm = (d == 0) ? bd : bd - 1,    zp = (d == Dd - 1) ? bd : bd + 1;
    // rows h0-1, h0, h0+1, h0+2 (clamped at volume faces)
    const int hr[4] = { (h0 == 0) ? 0 : h0 - 1, h0, h0 + 1,
                        (h0 + 2 > Hh - 1) ? Hh - 1 : h0 + 2 };
    const int zz[3] = { zm, bd, zp };

    // L/C/R[z][r]: value at (plane z, row r, w-1 / w / w+1). 36 loads.
    float L[3][4], C[3][4], R[3][4];
#pragma unroll
    for (int z = 0; z < 3; ++z) {
        const float* pl = x + (size_t)zz[z] * HW;
#pragma unroll
        for (int r = 0; r < 4; ++r) {
            const float* rp = pl + (size_t)hr[r] * Ww;
            L[z][r] = rp[wm];
            C[z][r] = rp[w];
            R[z][r] = rp[wp];
        }
    }

    // Shared part of the two 26-neighbor maxes: rows {1,2}, all z, all cols,
    // minus the two centers C[1][1], C[1][2]. 16 values.
    float sh = 0.0f;
#pragma unroll
    for (int z = 0; z < 3; ++z)
#pragma unroll
        for (int r = 1; r <= 2; ++r) {
            sh = fmaxf(sh, L[z][r]);
            sh = fmaxf(sh, R[z][r]);
            if (z != 1) sh = fmaxf(sh, C[z][r]);
        }

#pragma unroll
    for (int o = 0; o < 2; ++o) {
        const int r0 = o, r1 = o + 1, r2 = o + 2;
        const float xc = C[1][r1];

        // nmax = shared sub-max + exclusive row (r0 for o=0 is row0; the far
        // row for o=1 is row3) + the other output's center value.
        const int rx = (o == 0) ? 0 : 3;            // exclusive row
        float nm = sh;
#pragma unroll
        for (int z = 0; z < 3; ++z) {
            nm = fmaxf(nm, L[z][rx]);
            nm = fmaxf(nm, C[z][rx]);
            nm = fmaxf(nm, R[z][rx]);
        }
        nm = fmaxf(nm, C[1][(o == 0) ? 2 : 1]);     // other center is a neighbor
        const bool m = xc > nm;

        const float gx  = 0.5f * (R[1][r1] - L[1][r1]);
        const float gy  = 0.5f * (C[1][r2] - C[1][r0]);
        const float gs  = 0.5f * (C[2][r1] - C[0][r1]);
        const float dxx = L[1][r1] + R[1][r1] - 2.0f * xc;
        const float dyy = C[1][r0] + C[1][r2] - 2.0f * xc;
        const float dss = C[0][r1] + C[2][r1] - 2.0f * xc;
        const float dxy = 0.25f * (L[1][r0] + R[1][r2] - L[1][r2] - R[1][r0]);
        const float dys = 0.25f * (C[0][r0] + C[2][r2] - C[2][r0] - C[0][r2]);
        const float dxs = 0.25f * (L[0][r1] + R[2][r1] - L[2][r1] - R[0][r1]);

        // Cramer numerators of H*s = g. Rm eps (<=1e-7) dropped: near-singular
        // dets rejected by keep, like ref's far>0.7 clamp of eps-regularized dx.
        const float c00 = dyy * dss - dys * dys;
        const float c01 = dxy * dss - dys * dxs;
        const float c02 = dxy * dys - dyy * dxs;
        const float det = dxx * c00 - dxy * c01 + dxs * c02;
        const float t1  = gy * dss - dys * gs;
        const float t2  = gy * dys - dyy * gs;
        const float t3  = dxy * gs - gy * dxs;
        const float nx  = gx * c00 - dxy * t1 + dxs * t2;    // sx * det
        const float ny  = dxx * t1 - gx * c01 + dxs * t3;    // sy * det
        const float ns  = dxx * (-t2) - dxy * t3 + gx * c02; // ss * det

        // keep <=> m && det!=0 && all |num/det| <= 0.7, WITHOUT dividing.
        const float lim = 0.7f * fabsf(det);
        const bool keep = m && (fabsf(det) > 0.0f) &&
                          (fabsf(nx) <= lim) && (fabsf(ny) <= lim) && (fabsf(ns) <= lim);
        const float rdet = keep ? (1.0f / det) : 0.0f;
        const float dx0 = -nx * rdet;               // keep ? -nx/det : 0  (finite)
        const float dx1 = -ny * rdet;
        const float dx2 = -ns * rdet;

        const float dy_ = 0.5f * (gx * dx0 + gy * dx1 + gs * dx2);
        const float y   = xc + dy_ + (m ? BONUS_F : 0.0f);

        const size_t idx = (size_t)d * HW + (size_t)(h0 + o) * Ww + w;
        out[((size_t)(b * 3 + 0)) * DHW + idx] = (float)d + dx2;
        out[((size_t)(b * 3 + 1)) * DHW + idx] = (float)(h0 + o) + dx1;
        out[((size_t)(b * 3 + 2)) * DHW + idx] = (float)w + dx0;
        out[(size_t)6 * DHW + (size_t)b * DHW + idx] = y;
    }
}

extern "C" void kernel_launch(void* const* d_in, const int* in_sizes, int n_in,
                              void* d_out, int out_size, void* d_ws, size_t ws_size,
                              hipStream_t stream) {
    (void)in_sizes; (void)n_in; (void)out_size; (void)d_ws; (void)ws_size;
    const float* x = (const float*)d_in[0];
    float* out = (float*)d_out;
    dim3 block(64, 4, 1);
    dim3 grid(Ww / 64, Hh / 8, 2 * Dd);   // (8, 64, 20) = 10240 blocks
    quad_kernel<<<grid, block, 0, stream>>>(x, out);
}